// Round 18
// baseline (290.481 us; speedup 1.0000x reference)
//
#include <hip/hip_runtime.h>

typedef float f4 __attribute__((ext_vector_type(4)));

constexpr int NN = 100000;
constexpr int NE = 1600000;
constexpr int SCAN_BLK = 1024;
constexpr int NB = (NN + SCAN_BLK - 1) / SCAN_BLK;    // 98 scan blocks

__device__ __forceinline__ f4 relu_add(f4 a, f4 b) {
    f4 s = a + b;
    s.x = fmaxf(s.x, 0.f);
    s.y = fmaxf(s.y, 0.f);
    s.z = fmaxf(s.z, 0.f);
    s.w = fmaxf(s.w, 0.f);
    return s;
}

__device__ __forceinline__ f4 bf16x4_to_f4(uint2 u) {
    f4 r;
    r.x = __uint_as_float((u.x & 0xFFFFu) << 16);
    r.y = __uint_as_float(u.x & 0xFFFF0000u);
    r.z = __uint_as_float((u.y & 0xFFFFu) << 16);
    r.w = __uint_as_float(u.y & 0xFFFF0000u);
    return r;
}

__device__ __forceinline__ unsigned f2bf(float f) {
    unsigned u = __float_as_uint(f);
    return (u + 0x7FFFu + ((u >> 16) & 1u)) >> 16;   // round-to-nearest-even
}

__device__ __forceinline__ unsigned pack2bf(float lo, float hi) {
    return f2bf(lo) | (f2bf(hi) << 16);
}

// ---------------- fallback path (used only if ws too small) -------------------

__global__ __launch_bounds__(256) void k_init(const float* __restrict__ x,
                                              const float* __restrict__ eps,
                                              float* __restrict__ out) {
    const float s = 1.0f + eps[0];
    const float4* x4 = (const float4*)x;
    float4* o4 = (float4*)out;
    const int total = NN * 16;
    for (int i = blockIdx.x * blockDim.x + threadIdx.x; i < total;
         i += gridDim.x * blockDim.x) {
        float4 v = x4[i];
        v.x *= s; v.y *= s; v.z *= s; v.w *= s;
        o4[i] = v;
    }
}

__global__ __launch_bounds__(256) void k_edges(const float* __restrict__ x,
                                               const int* __restrict__ ei,
                                               const float* __restrict__ ea,
                                               float* __restrict__ out) {
    const int* dst = ei;
    const int* src = ei + NE;
    const float4* ea4 = (const float4*)ea;
    const float4* x4 = (const float4*)x;
    const int total = NE * 16;
    for (int g = blockIdx.x * blockDim.x + threadIdx.x; g < total;
         g += gridDim.x * blockDim.x) {
        const int e = g >> 4;
        const int c = g & 15;
        const int s = src[e];
        const int d = dst[e];
        float4 a  = ea4[g];
        float4 xv = x4[s * 16 + c];
        float* base = out + d * 64 + c * 4;
        atomicAdd(base + 0, fmaxf(xv.x + a.x, 0.0f));
        atomicAdd(base + 1, fmaxf(xv.y + a.y, 0.0f));
        atomicAdd(base + 2, fmaxf(xv.z + a.z, 0.0f));
        atomicAdd(base + 3, fmaxf(xv.w + a.w, 0.0f));
    }
}

__global__ __launch_bounds__(256) void k_linear2(const float* __restrict__ W,
                                                 const float* __restrict__ bias,
                                                 float* __restrict__ out) {
    __shared__ float Ws[64 * 64];
    __shared__ float bs[64];
    for (int i = threadIdx.x; i < 1024; i += 256)
        ((float4*)Ws)[i] = ((const float4*)W)[i];
    if (threadIdx.x < 16)
        ((float4*)bs)[threadIdx.x] = ((const float4*)bias)[threadIdx.x];
    __syncthreads();

    const int l16 = threadIdx.x & 15;
    const int gid = (blockIdx.x * 256 + threadIdx.x) >> 4;
    const float4* Ws4 = (const float4*)Ws;
    float4* out4 = (float4*)out;

    const float4 h4 = out4[gid * 16 + l16];
    float4 o = ((const float4*)bs)[l16];
#pragma unroll
    for (int d = 0; d < 64; ++d) {
        const int q = d >> 2;
        const int r = d & 3;
        float hd;
        if (r == 0)      hd = __shfl(h4.x, q, 16);
        else if (r == 1) hd = __shfl(h4.y, q, 16);
        else if (r == 2) hd = __shfl(h4.z, q, 16);
        else             hd = __shfl(h4.w, q, 16);
        const float4 w = Ws4[d * 16 + l16];
        o.x = fmaf(hd, w.x, o.x);
        o.y = fmaf(hd, w.y, o.y);
        o.z = fmaf(hd, w.z, o.z);
        o.w = fmaf(hd, w.w, o.w);
    }
    out4[gid * 16 + l16] = o;
}

// ---------------- main path ----------------------------------------------------

// fused: rank pass (side effect: cursor[] = per-node degree) + x -> bf16 table.
__global__ __launch_bounds__(256) void k_rank_cvt(const int* __restrict__ dst,
                                                  const float* __restrict__ x,
                                                  int* __restrict__ cursor,
                                                  int* __restrict__ rank,
                                                  unsigned short* __restrict__ xb) {
    const int tid = blockIdx.x * blockDim.x + threadIdx.x;
    const int nthr = gridDim.x * blockDim.x;

    // x conversion: 8 floats in (32B), 8 bf16 out (16B) per iteration
    const f4* x4 = (const f4*)x;
    uint4* xbo = (uint4*)xb;
    const int xtotal = NN * 8;
    for (int i = tid; i < xtotal; i += nthr) {
        const f4 a = x4[2 * i];
        const f4 b = x4[2 * i + 1];
        uint4 o;
        o.x = pack2bf(a.x, a.y);
        o.y = pack2bf(a.z, a.w);
        o.z = pack2bf(b.x, b.y);
        o.w = pack2bf(b.z, b.w);
        xbo[i] = o;
    }

    const int4* d4 = (const int4*)dst;
    int4* r4 = (int4*)rank;
    const int total = NE / 4;
    for (int i = tid; i < total; i += nthr) {
        const int4 d = d4[i];
        int4 r;
        r.x = atomicAdd(&cursor[d.x], 1);
        r.y = atomicAdd(&cursor[d.y], 1);
        r.z = atomicAdd(&cursor[d.z], 1);
        r.w = atomicAdd(&cursor[d.w], 1);
        r4[i] = r;
    }
}

__global__ __launch_bounds__(256) void k_scan_block(const int* __restrict__ counts,
                                                    int* __restrict__ offsets,
                                                    int* __restrict__ bsum) {
    __shared__ int sd[256];
    const int t = threadIdx.x;
    const int base = blockIdx.x * SCAN_BLK;
    int c[4];
    int s = 0;
#pragma unroll
    for (int k = 0; k < 4; ++k) {
        const int i = base + t * 4 + k;
        c[k] = (i < NN) ? counts[i] : 0;
        s += c[k];
    }
    sd[t] = s;
    __syncthreads();
#pragma unroll
    for (int off = 1; off < 256; off <<= 1) {
        int v = (t >= off) ? sd[t - off] : 0;
        __syncthreads();
        sd[t] += v;
        __syncthreads();
    }
    int excl = sd[t] - s;
#pragma unroll
    for (int k = 0; k < 4; ++k) {
        const int i = base + t * 4 + k;
        if (i < NN) offsets[i] = excl;
        excl += c[k];
    }
    if (t == 255) bsum[blockIdx.x] = sd[255];
}

// fused scan of the 98 block sums (redundant per block) + global fixup
__global__ __launch_bounds__(256) void k_scan_finish(int* __restrict__ offsets,
                                                     const int* __restrict__ bsum) {
    __shared__ int sd[128];
    const int t = threadIdx.x;
    if (t < 128) {
        const int v = (t < NB) ? bsum[t] : 0;
        sd[t] = v;
    }
    __syncthreads();
#pragma unroll
    for (int off = 1; off < 128; off <<= 1) {
        int u = 0;
        if (t < 128 && t >= off) u = sd[t - off];
        __syncthreads();
        if (t < 128) sd[t] += u;
        __syncthreads();
    }
    // sd now inclusive; exclusive base for block b is sd[b] - bsum[b]
    for (int i = blockIdx.x * blockDim.x + t; i < NN;
         i += gridDim.x * blockDim.x) {
        const int b = i >> 10;
        offsets[i] += sd[b] - bsum[b];
    }
    if (blockIdx.x == 0 && t == 0) offsets[NN] = NE;
}

// ATOMIC-FREE edge-order streaming value scatter, 4 edges per iteration.
// Index metadata via int4 vector loads (edges e0..e3 are consecutive) —
// 3 vector loads replace 12 redundant scalar loads per iteration.
__global__ __launch_bounds__(256) void k_scatter_val(const unsigned short* __restrict__ xb,
                                                     const int* __restrict__ ei,
                                                     const float* __restrict__ ea,
                                                     const int* __restrict__ offsets,
                                                     const int* __restrict__ rank,
                                                     unsigned short* __restrict__ vals) {
    const int4* d4 = (const int4*)ei;               // dst = ei[0..NE)
    const int4* s4 = (const int4*)(ei + NE);        // src = ei[NE..2NE)
    const int4* r4 = (const int4*)rank;
    const int l16 = threadIdx.x & 15;
    const int gid0 = (blockIdx.x * blockDim.x + threadIdx.x) >> 4;
    const int ngrp = (gridDim.x * blockDim.x) >> 4;
    const f4* ea4 = (const f4*)ea;
    uint2* v2 = (uint2*)vals;

    const int nbatch = NE / 4;               // 4 edges per group-iteration
    for (int bi = gid0; bi < nbatch; bi += ngrp) {
        const int4 dd = d4[bi];
        const int4 ss = s4[bi];
        const int4 rr = r4[bi];
        const int e0 = 4 * bi;
        const int slot0 = offsets[dd.x] + rr.x;
        const int slot1 = offsets[dd.y] + rr.y;
        const int slot2 = offsets[dd.z] + rr.z;
        const int slot3 = offsets[dd.w] + rr.w;
        const f4 A0 = ea4[(size_t)(e0 + 0) * 16 + l16];
        const f4 A1 = ea4[(size_t)(e0 + 1) * 16 + l16];
        const f4 A2 = ea4[(size_t)(e0 + 2) * 16 + l16];
        const f4 A3 = ea4[(size_t)(e0 + 3) * 16 + l16];
        const uint2 xu0 = *(const uint2*)&xb[(size_t)ss.x * 64 + l16 * 4];
        const uint2 xu1 = *(const uint2*)&xb[(size_t)ss.y * 64 + l16 * 4];
        const uint2 xu2 = *(const uint2*)&xb[(size_t)ss.z * 64 + l16 * 4];
        const uint2 xu3 = *(const uint2*)&xb[(size_t)ss.w * 64 + l16 * 4];
        const f4 m0 = relu_add(bf16x4_to_f4(xu0), A0);
        const f4 m1 = relu_add(bf16x4_to_f4(xu1), A1);
        const f4 m2 = relu_add(bf16x4_to_f4(xu2), A2);
        const f4 m3 = relu_add(bf16x4_to_f4(xu3), A3);
        uint2 o0, o1, o2, o3;
        o0.x = pack2bf(m0.x, m0.y); o0.y = pack2bf(m0.z, m0.w);
        o1.x = pack2bf(m1.x, m1.y); o1.y = pack2bf(m1.z, m1.w);
        o2.x = pack2bf(m2.x, m2.y); o2.y = pack2bf(m2.z, m2.w);
        o3.x = pack2bf(m3.x, m3.y); o3.y = pack2bf(m3.z, m3.w);
        v2[(size_t)slot0 * 16 + l16] = o0;
        v2[(size_t)slot1 * 16 + l16] = o1;
        v2[(size_t)slot2 * 16 + l16] = o2;
        v2[(size_t)slot3 * 16 + l16] = o3;
    }
}

// Streaming segmented sum + self-term + fused linear. 8-deep unroll for
// deeper L3-latency hiding on the vals stream.
__global__ __launch_bounds__(256) void k_segsum_lin(const float* __restrict__ x,
                                                    const unsigned short* __restrict__ vals,
                                                    const int* __restrict__ offsets,
                                                    const float* __restrict__ epsp,
                                                    const float* __restrict__ W,
                                                    const float* __restrict__ bias,
                                                    float* __restrict__ out) {
    __shared__ float Ws[64 * 64];
    __shared__ float bs[64];
    for (int i = threadIdx.x; i < 1024; i += 256)
        ((float4*)Ws)[i] = ((const float4*)W)[i];
    if (threadIdx.x < 16)
        ((float4*)bs)[threadIdx.x] = ((const float4*)bias)[threadIdx.x];
    __syncthreads();

    const float epsv = 1.0f + epsp[0];
    const int l16 = threadIdx.x & 15;
    const int n = (blockIdx.x * 256 + threadIdx.x) >> 4;   // node id, < NN exact
    const f4* x4 = (const f4*)x;
    const uint2* v2 = (const uint2*)vals;
    const f4* Ws4 = (const f4*)Ws;
    f4* out4 = (f4*)out;

    const int beg = offsets[n];
    const int end = offsets[n + 1];
    f4 acc = {0.f, 0.f, 0.f, 0.f};

    int j = beg;
    for (; j + 8 <= end; j += 8) {               // 8 rows in flight
        const uint2 u0 = v2[(size_t)(j + 0) * 16 + l16];
        const uint2 u1 = v2[(size_t)(j + 1) * 16 + l16];
        const uint2 u2 = v2[(size_t)(j + 2) * 16 + l16];
        const uint2 u3 = v2[(size_t)(j + 3) * 16 + l16];
        const uint2 u4 = v2[(size_t)(j + 4) * 16 + l16];
        const uint2 u5 = v2[(size_t)(j + 5) * 16 + l16];
        const uint2 u6 = v2[(size_t)(j + 6) * 16 + l16];
        const uint2 u7 = v2[(size_t)(j + 7) * 16 + l16];
        acc += bf16x4_to_f4(u0) + bf16x4_to_f4(u1) +
               bf16x4_to_f4(u2) + bf16x4_to_f4(u3);
        acc += bf16x4_to_f4(u4) + bf16x4_to_f4(u5) +
               bf16x4_to_f4(u6) + bf16x4_to_f4(u7);
    }
    for (; j + 4 <= end; j += 4) {
        const uint2 u0 = v2[(size_t)(j + 0) * 16 + l16];
        const uint2 u1 = v2[(size_t)(j + 1) * 16 + l16];
        const uint2 u2 = v2[(size_t)(j + 2) * 16 + l16];
        const uint2 u3 = v2[(size_t)(j + 3) * 16 + l16];
        acc += bf16x4_to_f4(u0) + bf16x4_to_f4(u1) +
               bf16x4_to_f4(u2) + bf16x4_to_f4(u3);
    }
    for (; j < end; ++j)
        acc += bf16x4_to_f4(v2[(size_t)j * 16 + l16]);

    // self term from exact fp32 x
    const f4 xs = x4[n * 16 + l16];
    f4 h;
    h.x = fmaf(xs.x, epsv, acc.x);
    h.y = fmaf(xs.y, epsv, acc.y);
    h.z = fmaf(xs.z, epsv, acc.z);
    h.w = fmaf(xs.w, epsv, acc.w);

    // fused linear: o[l16*4+k] = b + sum_d h[d] * W[d][l16*4+k]
    f4 o = ((const f4*)bs)[l16];
#pragma unroll
    for (int d = 0; d < 64; ++d) {
        const int q = d >> 2;
        const int r = d & 3;
        float hd;
        if (r == 0)      hd = __shfl(h.x, q, 16);
        else if (r == 1) hd = __shfl(h.y, q, 16);
        else if (r == 2) hd = __shfl(h.z, q, 16);
        else             hd = __shfl(h.w, q, 16);
        const f4 w = Ws4[d * 16 + l16];
        o.x = fmaf(hd, w.x, o.x);
        o.y = fmaf(hd, w.y, o.y);
        o.z = fmaf(hd, w.z, o.z);
        o.w = fmaf(hd, w.w, o.w);
    }
    out4[n * 16 + l16] = o;
}

extern "C" void kernel_launch(void* const* d_in, const int* in_sizes, int n_in,
                              void* d_out, int out_size, void* d_ws, size_t ws_size,
                              hipStream_t stream) {
    const float* x   = (const float*)d_in[0];
    const int*   ei  = (const int*)d_in[1];
    const float* ea  = (const float*)d_in[2];
    const float* eps = (const float*)d_in[3];
    const float* W   = (const float*)d_in[4];
    const float* b   = (const float*)d_in[5];
    float* out = (float*)d_out;

    const int* dst = ei;        // edge_index[0]

    // workspace layout: vals (16B-aligned at base), xb, rank, ints
    unsigned short* vals = (unsigned short*)d_ws;      // NE*64 bf16 (204.8 MB)
    unsigned short* xb   = vals + (size_t)NE * 64;     // NN*64 bf16 (12.8 MB)
    int* rank    = (int*)(xb + (size_t)NN * 64);       // NE (6.4 MB)
    int* cursor  = rank + NE;                          // NN (counts after rank)
    int* offsets = cursor + NN;                        // NN + 1
    int* bsum    = offsets + NN + 1;                   // 128
    const size_t ws_needed = (size_t)NE * 128 + (size_t)NN * 128 +
                             (size_t)NE * 4 +
                             (size_t)(2 * NN + 1 + 128) * sizeof(int);

    if (ws_size < ws_needed) {            // insurance: atomic fallback
        k_init<<<2048, 256, 0, stream>>>(x, eps, out);
        k_edges<<<2048, 256, 0, stream>>>(x, ei, ea, out);
        k_linear2<<<NN * 16 / 256, 256, 0, stream>>>(W, b, out);
        return;
    }

    (void)hipMemsetAsync(cursor, 0, (size_t)NN * sizeof(int), stream);
    k_rank_cvt<<<1024, 256, 0, stream>>>(dst, x, cursor, rank, xb);
    k_scan_block<<<NB, 256, 0, stream>>>(cursor, offsets, bsum);
    k_scan_finish<<<256, 256, 0, stream>>>(offsets, bsum);
    k_scatter_val<<<4096, 256, 0, stream>>>(xb, ei, ea, offsets, rank, vals);
    k_segsum_lin<<<NN * 16 / 256, 256, 0, stream>>>(x, vals, offsets, eps,
                                                    W, b, out);
}

// Round 19
// 281.268 us; speedup vs baseline: 1.0328x; 1.0328x over previous
//
#include <hip/hip_runtime.h>

typedef float f4 __attribute__((ext_vector_type(4)));

constexpr int NN = 100000;
constexpr int NE = 1600000;
constexpr int SCAN_BLK = 1024;
constexpr int NB = (NN + SCAN_BLK - 1) / SCAN_BLK;    // 98 scan blocks

__device__ __forceinline__ f4 relu_add(f4 a, f4 b) {
    f4 s = a + b;
    s.x = fmaxf(s.x, 0.f);
    s.y = fmaxf(s.y, 0.f);
    s.z = fmaxf(s.z, 0.f);
    s.w = fmaxf(s.w, 0.f);
    return s;
}

__device__ __forceinline__ f4 bf16x4_to_f4(uint2 u) {
    f4 r;
    r.x = __uint_as_float((u.x & 0xFFFFu) << 16);
    r.y = __uint_as_float(u.x & 0xFFFF0000u);
    r.z = __uint_as_float((u.y & 0xFFFFu) << 16);
    r.w = __uint_as_float(u.y & 0xFFFF0000u);
    return r;
}

__device__ __forceinline__ unsigned f2bf(float f) {
    unsigned u = __float_as_uint(f);
    return (u + 0x7FFFu + ((u >> 16) & 1u)) >> 16;   // round-to-nearest-even
}

__device__ __forceinline__ unsigned pack2bf(float lo, float hi) {
    return f2bf(lo) | (f2bf(hi) << 16);
}

// ---------------- fallback path (used only if ws too small) -------------------

__global__ __launch_bounds__(256) void k_init(const float* __restrict__ x,
                                              const float* __restrict__ eps,
                                              float* __restrict__ out) {
    const float s = 1.0f + eps[0];
    const float4* x4 = (const float4*)x;
    float4* o4 = (float4*)out;
    const int total = NN * 16;
    for (int i = blockIdx.x * blockDim.x + threadIdx.x; i < total;
         i += gridDim.x * blockDim.x) {
        float4 v = x4[i];
        v.x *= s; v.y *= s; v.z *= s; v.w *= s;
        o4[i] = v;
    }
}

__global__ __launch_bounds__(256) void k_edges(const float* __restrict__ x,
                                               const int* __restrict__ ei,
                                               const float* __restrict__ ea,
                                               float* __restrict__ out) {
    const int* dst = ei;
    const int* src = ei + NE;
    const float4* ea4 = (const float4*)ea;
    const float4* x4 = (const float4*)x;
    const int total = NE * 16;
    for (int g = blockIdx.x * blockDim.x + threadIdx.x; g < total;
         g += gridDim.x * blockDim.x) {
        const int e = g >> 4;
        const int c = g & 15;
        const int s = src[e];
        const int d = dst[e];
        float4 a  = ea4[g];
        float4 xv = x4[s * 16 + c];
        float* base = out + d * 64 + c * 4;
        atomicAdd(base + 0, fmaxf(xv.x + a.x, 0.0f));
        atomicAdd(base + 1, fmaxf(xv.y + a.y, 0.0f));
        atomicAdd(base + 2, fmaxf(xv.z + a.z, 0.0f));
        atomicAdd(base + 3, fmaxf(xv.w + a.w, 0.0f));
    }
}

__global__ __launch_bounds__(256) void k_linear2(const float* __restrict__ W,
                                                 const float* __restrict__ bias,
                                                 float* __restrict__ out) {
    __shared__ float Ws[64 * 64];
    __shared__ float bs[64];
    for (int i = threadIdx.x; i < 1024; i += 256)
        ((float4*)Ws)[i] = ((const float4*)W)[i];
    if (threadIdx.x < 16)
        ((float4*)bs)[threadIdx.x] = ((const float4*)bias)[threadIdx.x];
    __syncthreads();

    const int l16 = threadIdx.x & 15;
    const int gid = (blockIdx.x * 256 + threadIdx.x) >> 4;
    const float4* Ws4 = (const float4*)Ws;
    float4* out4 = (float4*)out;

    const float4 h4 = out4[gid * 16 + l16];
    float4 o = ((const float4*)bs)[l16];
#pragma unroll
    for (int d = 0; d < 64; ++d) {
        const int q = d >> 2;
        const int r = d & 3;
        float hd;
        if (r == 0)      hd = __shfl(h4.x, q, 16);
        else if (r == 1) hd = __shfl(h4.y, q, 16);
        else if (r == 2) hd = __shfl(h4.z, q, 16);
        else             hd = __shfl(h4.w, q, 16);
        const float4 w = Ws4[d * 16 + l16];
        o.x = fmaf(hd, w.x, o.x);
        o.y = fmaf(hd, w.y, o.y);
        o.z = fmaf(hd, w.z, o.z);
        o.w = fmaf(hd, w.w, o.w);
    }
    out4[gid * 16 + l16] = o;
}

// ---------------- main path ----------------------------------------------------

// fused: rank pass (side effect: cursor[] = per-node degree) + x -> bf16 table.
// The streaming cvt rides under the atomic-latency-bound rank loop.
__global__ __launch_bounds__(256) void k_rank_cvt(const int* __restrict__ dst,
                                                  const float* __restrict__ x,
                                                  int* __restrict__ cursor,
                                                  int* __restrict__ rank,
                                                  unsigned short* __restrict__ xb) {
    const int tid = blockIdx.x * blockDim.x + threadIdx.x;
    const int nthr = gridDim.x * blockDim.x;

    // x conversion: 8 floats in (32B), 8 bf16 out (16B) per iteration
    const f4* x4 = (const f4*)x;
    uint4* xbo = (uint4*)xb;
    const int xtotal = NN * 8;
    for (int i = tid; i < xtotal; i += nthr) {
        const f4 a = x4[2 * i];
        const f4 b = x4[2 * i + 1];
        uint4 o;
        o.x = pack2bf(a.x, a.y);
        o.y = pack2bf(a.z, a.w);
        o.z = pack2bf(b.x, b.y);
        o.w = pack2bf(b.z, b.w);
        xbo[i] = o;
    }

    const int4* d4 = (const int4*)dst;
    int4* r4 = (int4*)rank;
    const int total = NE / 4;
    for (int i = tid; i < total; i += nthr) {
        const int4 d = d4[i];
        int4 r;
        r.x = atomicAdd(&cursor[d.x], 1);
        r.y = atomicAdd(&cursor[d.y], 1);
        r.z = atomicAdd(&cursor[d.z], 1);
        r.w = atomicAdd(&cursor[d.w], 1);
        r4[i] = r;
    }
}

__global__ __launch_bounds__(256) void k_scan_block(const int* __restrict__ counts,
                                                    int* __restrict__ offsets,
                                                    int* __restrict__ bsum) {
    __shared__ int sd[256];
    const int t = threadIdx.x;
    const int base = blockIdx.x * SCAN_BLK;
    int c[4];
    int s = 0;
#pragma unroll
    for (int k = 0; k < 4; ++k) {
        const int i = base + t * 4 + k;
        c[k] = (i < NN) ? counts[i] : 0;
        s += c[k];
    }
    sd[t] = s;
    __syncthreads();
#pragma unroll
    for (int off = 1; off < 256; off <<= 1) {
        int v = (t >= off) ? sd[t - off] : 0;
        __syncthreads();
        sd[t] += v;
        __syncthreads();
    }
    int excl = sd[t] - s;
#pragma unroll
    for (int k = 0; k < 4; ++k) {
        const int i = base + t * 4 + k;
        if (i < NN) offsets[i] = excl;
        excl += c[k];
    }
    if (t == 255) bsum[blockIdx.x] = sd[255];
}

// fused scan of the 98 block sums (redundant per block) + global fixup
__global__ __launch_bounds__(256) void k_scan_finish(int* __restrict__ offsets,
                                                     const int* __restrict__ bsum) {
    __shared__ int sd[128];
    const int t = threadIdx.x;
    if (t < 128) {
        const int v = (t < NB) ? bsum[t] : 0;
        sd[t] = v;
    }
    __syncthreads();
#pragma unroll
    for (int off = 1; off < 128; off <<= 1) {
        int u = 0;
        if (t < 128 && t >= off) u = sd[t - off];
        __syncthreads();
        if (t < 128) sd[t] += u;
        __syncthreads();
    }
    // sd now inclusive; exclusive base for block b is sd[b] - bsum[b]
    for (int i = blockIdx.x * blockDim.x + t; i < NN;
         i += gridDim.x * blockDim.x) {
        const int b = i >> 10;
        offsets[i] += sd[b] - bsum[b];
    }
    if (blockIdx.x == 0 && t == 0) offsets[NN] = NE;
}

// ATOMIC-FREE edge-order streaming value scatter, 4 edges per iteration.
// slot = offsets[dst[e]] + rank[e] — pure loads. ea read is sequential fp32;
// x gathered from the 12.8MB bf16 table (halves gather traffic vs fp32).
// Writes bf16 128B rows into the dst-sorted 205MB L3-resident value buffer.
__global__ __launch_bounds__(256) void k_scatter_val(const unsigned short* __restrict__ xb,
                                                     const int* __restrict__ ei,
                                                     const float* __restrict__ ea,
                                                     const int* __restrict__ offsets,
                                                     const int* __restrict__ rank,
                                                     unsigned short* __restrict__ vals) {
    const int* dst = ei;
    const int* src = ei + NE;
    const int l16 = threadIdx.x & 15;
    const int gid0 = (blockIdx.x * blockDim.x + threadIdx.x) >> 4;
    const int ngrp = (gridDim.x * blockDim.x) >> 4;
    const f4* ea4 = (const f4*)ea;
    uint2* v2 = (uint2*)vals;

    const int nbatch = NE / 4;               // 4 edges per group-iteration
    for (int bi = gid0; bi < nbatch; bi += ngrp) {
        const int e0 = 4 * bi, e1 = e0 + 1, e2 = e0 + 2, e3 = e0 + 3;
        const int d0 = dst[e0], d1 = dst[e1], d2 = dst[e2], d3 = dst[e3];
        const int s0 = src[e0], s1 = src[e1], s2 = src[e2], s3 = src[e3];
        const int slot0 = offsets[d0] + rank[e0];
        const int slot1 = offsets[d1] + rank[e1];
        const int slot2 = offsets[d2] + rank[e2];
        const int slot3 = offsets[d3] + rank[e3];
        const f4 A0 = ea4[(size_t)e0 * 16 + l16];
        const f4 A1 = ea4[(size_t)e1 * 16 + l16];
        const f4 A2 = ea4[(size_t)e2 * 16 + l16];
        const f4 A3 = ea4[(size_t)e3 * 16 + l16];
        const uint2 xu0 = *(const uint2*)&xb[(size_t)s0 * 64 + l16 * 4];
        const uint2 xu1 = *(const uint2*)&xb[(size_t)s1 * 64 + l16 * 4];
        const uint2 xu2 = *(const uint2*)&xb[(size_t)s2 * 64 + l16 * 4];
        const uint2 xu3 = *(const uint2*)&xb[(size_t)s3 * 64 + l16 * 4];
        const f4 m0 = relu_add(bf16x4_to_f4(xu0), A0);
        const f4 m1 = relu_add(bf16x4_to_f4(xu1), A1);
        const f4 m2 = relu_add(bf16x4_to_f4(xu2), A2);
        const f4 m3 = relu_add(bf16x4_to_f4(xu3), A3);
        uint2 o0, o1, o2, o3;
        o0.x = pack2bf(m0.x, m0.y); o0.y = pack2bf(m0.z, m0.w);
        o1.x = pack2bf(m1.x, m1.y); o1.y = pack2bf(m1.z, m1.w);
        o2.x = pack2bf(m2.x, m2.y); o2.y = pack2bf(m2.z, m2.w);
        o3.x = pack2bf(m3.x, m3.y); o3.y = pack2bf(m3.z, m3.w);
        v2[(size_t)slot0 * 16 + l16] = o0;
        v2[(size_t)slot1 * 16 + l16] = o1;
        v2[(size_t)slot2 * 16 + l16] = o2;
        v2[(size_t)slot3 * 16 + l16] = o3;
    }
}

// Streaming segmented sum + self-term + fused linear.
// One node per 16-lane group (6250 blocks exact); contiguous bf16 rows.
__global__ __launch_bounds__(256) void k_segsum_lin(const float* __restrict__ x,
                                                    const unsigned short* __restrict__ vals,
                                                    const int* __restrict__ offsets,
                                                    const float* __restrict__ epsp,
                                                    const float* __restrict__ W,
                                                    const float* __restrict__ bias,
                                                    float* __restrict__ out) {
    __shared__ float Ws[64 * 64];
    __shared__ float bs[64];
    for (int i = threadIdx.x; i < 1024; i += 256)
        ((float4*)Ws)[i] = ((const float4*)W)[i];
    if (threadIdx.x < 16)
        ((float4*)bs)[threadIdx.x] = ((const float4*)bias)[threadIdx.x];
    __syncthreads();

    const float epsv = 1.0f + epsp[0];
    const int l16 = threadIdx.x & 15;
    const int n = (blockIdx.x * 256 + threadIdx.x) >> 4;   // node id, < NN exact
    const f4* x4 = (const f4*)x;
    const uint2* v2 = (const uint2*)vals;
    const f4* Ws4 = (const f4*)Ws;
    f4* out4 = (f4*)out;

    const int beg = offsets[n];
    const int end = offsets[n + 1];
    f4 acc = {0.f, 0.f, 0.f, 0.f};

    int j = beg;
    for (; j + 4 <= end; j += 4) {               // sequential 128B rows
        const uint2 u0 = v2[(size_t)(j + 0) * 16 + l16];
        const uint2 u1 = v2[(size_t)(j + 1) * 16 + l16];
        const uint2 u2 = v2[(size_t)(j + 2) * 16 + l16];
        const uint2 u3 = v2[(size_t)(j + 3) * 16 + l16];
        acc += bf16x4_to_f4(u0) + bf16x4_to_f4(u1) +
               bf16x4_to_f4(u2) + bf16x4_to_f4(u3);
    }
    for (; j < end; ++j)
        acc += bf16x4_to_f4(v2[(size_t)j * 16 + l16]);

    // self term from exact fp32 x
    const f4 xs = x4[n * 16 + l16];
    f4 h;
    h.x = fmaf(xs.x, epsv, acc.x);
    h.y = fmaf(xs.y, epsv, acc.y);
    h.z = fmaf(xs.z, epsv, acc.z);
    h.w = fmaf(xs.w, epsv, acc.w);

    // fused linear: o[l16*4+k] = b + sum_d h[d] * W[d][l16*4+k]
    f4 o = ((const f4*)bs)[l16];
#pragma unroll
    for (int d = 0; d < 64; ++d) {
        const int q = d >> 2;
        const int r = d & 3;
        float hd;
        if (r == 0)      hd = __shfl(h.x, q, 16);
        else if (r == 1) hd = __shfl(h.y, q, 16);
        else if (r == 2) hd = __shfl(h.z, q, 16);
        else             hd = __shfl(h.w, q, 16);
        const f4 w = Ws4[d * 16 + l16];
        o.x = fmaf(hd, w.x, o.x);
        o.y = fmaf(hd, w.y, o.y);
        o.z = fmaf(hd, w.z, o.z);
        o.w = fmaf(hd, w.w, o.w);
    }
    out4[n * 16 + l16] = o;
}

extern "C" void kernel_launch(void* const* d_in, const int* in_sizes, int n_in,
                              void* d_out, int out_size, void* d_ws, size_t ws_size,
                              hipStream_t stream) {
    const float* x   = (const float*)d_in[0];
    const int*   ei  = (const int*)d_in[1];
    const float* ea  = (const float*)d_in[2];
    const float* eps = (const float*)d_in[3];
    const float* W   = (const float*)d_in[4];
    const float* b   = (const float*)d_in[5];
    float* out = (float*)d_out;

    const int* dst = ei;        // edge_index[0]

    // workspace layout: vals (16B-aligned at base), xb, rank, ints
    unsigned short* vals = (unsigned short*)d_ws;      // NE*64 bf16 (204.8 MB)
    unsigned short* xb   = vals + (size_t)NE * 64;     // NN*64 bf16 (12.8 MB)
    int* rank    = (int*)(xb + (size_t)NN * 64);       // NE (6.4 MB)
    int* cursor  = rank + NE;                          // NN (counts after rank)
    int* offsets = cursor + NN;                        // NN + 1
    int* bsum    = offsets + NN + 1;                   // 128
    const size_t ws_needed = (size_t)NE * 128 + (size_t)NN * 128 +
                             (size_t)NE * 4 +
                             (size_t)(2 * NN + 1 + 128) * sizeof(int);

    if (ws_size < ws_needed) {            // insurance: atomic fallback
        k_init<<<2048, 256, 0, stream>>>(x, eps, out);
        k_edges<<<2048, 256, 0, stream>>>(x, ei, ea, out);
        k_linear2<<<NN * 16 / 256, 256, 0, stream>>>(W, b, out);
        return;
    }

    (void)hipMemsetAsync(cursor, 0, (size_t)NN * sizeof(int), stream);
    k_rank_cvt<<<1024, 256, 0, stream>>>(dst, x, cursor, rank, xb);
    k_scan_block<<<NB, 256, 0, stream>>>(cursor, offsets, bsum);
    k_scan_finish<<<256, 256, 0, stream>>>(offsets, bsum);
    k_scatter_val<<<4096, 256, 0, stream>>>(xb, ei, ea, offsets, rank, vals);
    k_segsum_lin<<<NN * 16 / 256, 256, 0, stream>>>(x, vals, offsets, eps,
                                                    W, b, out);
}